// Round 5
// baseline (300.905 us; speedup 1.0000x reference)
//
#include <hip/hip_runtime.h>
#include <stdint.h>

constexpr int Bn = 8;
constexpr int Nn = 16384;
constexpr int Dn = 128;
constexpr int On = 256;
#define LN_EPS 1e-5f

typedef float  f32x4 __attribute__((ext_vector_type(4)));
typedef short  s16x8 __attribute__((ext_vector_type(8)));

__device__ __forceinline__ unsigned short f2bf(float f) {
    union { float f; unsigned u; } v; v.f = f;
    unsigned r = v.u + 0x7FFFu + ((v.u >> 16) & 1u);   // RNE
    return (unsigned short)(r >> 16);
}
__device__ __forceinline__ float bf2f(unsigned short s) {
    unsigned u = ((unsigned)s) << 16;
    float f; __builtin_memcpy(&f, &u, 4);
    return f;
}

// ------------------------------------------------------------------
// K2 v6: round-2 structure + SOFTWARE-PIPELINED n-loop.
// Theory (r4): per-sc phases {load -> wait ~900cy -> pack -> bar ->
// MFMA -> bar} expose full HBM latency 4x per block with only 2
// blocks/CU to cover it. Loads go to REGISTERS, so sc+1's loads can
// issue right after the first barrier and fly under the MFMA+cs
// phase (no vmcnt drain needed at s_barrier for reg-destined loads).
// Same math, grid, LDS layout as round 4; +64 VGPR prefetch state.
// ------------------------------------------------------------------
__global__ __launch_bounds__(256) void k_context(
    const float* __restrict__ x1, const float* __restrict__ x2,
    float* __restrict__ ctx_part, float* __restrict__ cs_part)
{
    __shared__ unsigned short As[128][72];
    __shared__ unsigned short Bs[128][72];
    __shared__ float cs_scr[256];

    const int b     = blockIdx.y;
    const int chunk = blockIdx.x;
    const int t     = threadIdx.x;
    const int wave  = t >> 6;
    const int lane  = t & 63;
    const int c     = lane & 15, g = lane >> 4;

    const int n_base = chunk * 256;

    f32x4 acc[2][8];
    #pragma unroll
    for (int i = 0; i < 2; ++i)
        #pragma unroll
        for (int j = 0; j < 8; ++j) acc[i][j] = (f32x4){0.f,0.f,0.f,0.f};

    const int dg = t >> 5, rg = t & 31;
    const int d0 = dg * 16;

    float cs_acc = 0.f;
    const int cd = t & 127, half = t >> 7;

    const float* p1base = x1 + (((long)b * Nn + n_base + 2 * rg) * Dn + d0);
    const float* p2base = x2 + (((long)b * Nn + n_base + 2 * rg) * Dn + d0);

    f32x4 r1a[4], r1b[4], r2a[4], r2b[4];
    // prologue: load sc=0
    #pragma unroll
    for (int j = 0; j < 4; ++j) {
        r1a[j] = *(const f32x4*)(p1base + j * 4);
        r1b[j] = *(const f32x4*)(p1base + Dn + j * 4);
        r2a[j] = *(const f32x4*)(p2base + j * 4);
        r2b[j] = *(const f32x4*)(p2base + Dn + j * 4);
    }

    for (int sc = 0; sc < 4; ++sc) {
        // ---- pack current regs -> LDS ----
        #pragma unroll
        for (int j = 0; j < 4; ++j) {
            #pragma unroll
            for (int jj = 0; jj < 4; ++jj) {
                const int d = d0 + j * 4 + jj;
                unsigned ua = (unsigned)f2bf(__expf(r1a[j][jj])) |
                              ((unsigned)f2bf(__expf(r1b[j][jj])) << 16);
                unsigned ub = (unsigned)f2bf(r2a[j][jj]) |
                              ((unsigned)f2bf(r2b[j][jj]) << 16);
                *(unsigned*)&As[d][2 * rg] = ua;
                *(unsigned*)&Bs[d][2 * rg] = ub;
            }
        }
        __syncthreads();

        // ---- issue next chunk's loads; they fly under MFMA+cs ----
        if (sc < 3) {
            const float* p1 = p1base + (long)(sc + 1) * 64 * Dn;
            const float* p2 = p2base + (long)(sc + 1) * 64 * Dn;
            #pragma unroll
            for (int j = 0; j < 4; ++j) {
                r1a[j] = *(const f32x4*)(p1 + j * 4);
                r1b[j] = *(const f32x4*)(p1 + Dn + j * 4);
                r2a[j] = *(const f32x4*)(p2 + j * 4);
                r2b[j] = *(const f32x4*)(p2 + Dn + j * 4);
            }
        }

        // ---- cs-sum + MFMA from LDS ----
        #pragma unroll
        for (int j = 0; j < 4; ++j) {
            const s16x8 e = *(const s16x8*)&As[cd][half * 32 + j * 8];
            #pragma unroll
            for (int jj = 0; jj < 8; ++jj)
                cs_acc += bf2f((unsigned short)e[jj]);
        }
        #pragma unroll
        for (int kk = 0; kk < 2; ++kk) {
            s16x8 a[2], bb[8];
            #pragma unroll
            for (int mt = 0; mt < 2; ++mt)
                a[mt] = *(const s16x8*)&As[wave * 32 + mt * 16 + c][kk * 32 + g * 8];
            #pragma unroll
            for (int nt = 0; nt < 8; ++nt)
                bb[nt] = *(const s16x8*)&Bs[nt * 16 + c][kk * 32 + g * 8];
            #pragma unroll
            for (int mt = 0; mt < 2; ++mt)
                #pragma unroll
                for (int nt = 0; nt < 8; ++nt)
                    acc[mt][nt] = __builtin_amdgcn_mfma_f32_16x16x32_bf16(
                        a[mt], bb[nt], acc[mt][nt], 0, 0, 0);
        }
        __syncthreads();
    }

    cs_scr[t] = cs_acc;
    __syncthreads();
    if (t < 128)
        cs_part[((long)(b * 64 + chunk)) * 128 + t] = cs_scr[t] + cs_scr[t + 128];

    float* cp = ctx_part + ((long)(b * 64 + chunk)) * 16384;
    #pragma unroll
    for (int mt = 0; mt < 2; ++mt)
        #pragma unroll
        for (int nt = 0; nt < 8; ++nt)
            #pragma unroll
            for (int r = 0; r < 4; ++r) {
                int d = wave * 32 + mt * 16 + g * 4 + r;
                int v = nt * 16 + c;
                cp[d * 128 + v] = acc[mt][nt][r];
            }
}

// ------------------------------------------------------------------
// K2b (unchanged from round 4): reduce 64 chunk-partials.
// ------------------------------------------------------------------
__global__ __launch_bounds__(256) void k_reduce(
    const float* __restrict__ ctx_part, const float* __restrict__ cs_part,
    float* __restrict__ ctx, float* __restrict__ cs)
{
    const int gid = blockIdx.x * 256 + threadIdx.x;   // 0..32767
    const long F  = (long)gid * 4;
    const int b   = gid >> 12;
    const int f   = (int)(F & 16383);

    const float* base = ctx_part + ((long)b * 64) * 16384 + f;
    f32x4 s = (f32x4){0.f, 0.f, 0.f, 0.f};
    #pragma unroll 8
    for (int ck = 0; ck < 64; ++ck) {
        f32x4 v = *(const f32x4*)(base + (long)ck * 16384);
        s[0] += v[0]; s[1] += v[1]; s[2] += v[2]; s[3] += v[3];
    }
    *(f32x4*)(ctx + F) = s;

    if (gid < 1024) {
        const int bb = gid >> 7, d = gid & 127;
        const float* cb = cs_part + ((long)bb * 64) * 128 + d;
        float sc = 0.f;
        #pragma unroll 8
        for (int ck = 0; ck < 64; ++ck) sc += cb[ck * 128];
        cs[gid] = sc;
    }
}

// ------------------------------------------------------------------
// K3 v2 (unchanged): Mt[b][o][d] = bf16( (ctx[b][d][:] . w[o][:]) / cs[b][d] )
// ------------------------------------------------------------------
__global__ __launch_bounds__(256) void k_mt(
    const float* __restrict__ ctx, const float* __restrict__ cs,
    const float* __restrict__ w, unsigned short* __restrict__ Mt)
{
    const int b = blockIdx.y;
    const int t = threadIdx.x;
    const int o = blockIdx.x * 2 + (t >> 7);
    const int d = t & 127;

    const float* crow = ctx + ((long)b * 128 + d) * 128;
    const float* wrow = w + (long)o * 128;

    float s0 = 0.f, s1 = 0.f, s2 = 0.f, s3 = 0.f;
    #pragma unroll
    for (int v = 0; v < 128; v += 16) {
        f32x4 c0 = *(const f32x4*)(crow + v);
        f32x4 c1 = *(const f32x4*)(crow + v + 4);
        f32x4 c2 = *(const f32x4*)(crow + v + 8);
        f32x4 c3 = *(const f32x4*)(crow + v + 12);
        f32x4 w0 = *(const f32x4*)(wrow + v);
        f32x4 w1 = *(const f32x4*)(wrow + v + 4);
        f32x4 w2 = *(const f32x4*)(wrow + v + 8);
        f32x4 w3 = *(const f32x4*)(wrow + v + 12);
        s0 += c0[0]*w0[0] + c0[1]*w0[1] + c0[2]*w0[2] + c0[3]*w0[3];
        s1 += c1[0]*w1[0] + c1[1]*w1[1] + c1[2]*w1[2] + c1[3]*w1[3];
        s2 += c2[0]*w2[0] + c2[1]*w2[1] + c2[2]*w2[2] + c2[3]*w2[3];
        s3 += c3[0]*w3[0] + c3[1]*w3[1] + c3[2]*w3[2] + c3[3]*w3[3];
    }
    const float s = (s0 + s1) + (s2 + s3);
    Mt[((long)b * On + o) * 128 + d] = f2bf(s / cs[b * 128 + d]);
}

// ------------------------------------------------------------------
// K4 v5 (unchanged from round 4): full-line output stores via LDS
// transpose (MtL reuse). Round-4 verified: removed the write-allocate
// RMW (round-3: FETCH +128 MB, WRITE 301 MB).
// ------------------------------------------------------------------
__global__ __launch_bounds__(512, 4) void k_main(
    const float* __restrict__ x1, const unsigned short* __restrict__ Mt,
    const float* __restrict__ bias, const float* __restrict__ gamma,
    const float* __restrict__ beta, float* __restrict__ out)
{
    __shared__ unsigned short MtL[256 * 128];   // 64 KiB; reused as out-stage

    const int b    = blockIdx.y;
    const int t    = threadIdx.x;
    const int wave = t >> 6, lane = t & 63;
    const int c    = lane & 15, g = lane >> 4;
    const int row  = blockIdx.x * 128 + wave * 16 + c;

    // ---- stage Mt -> LDS (swizzled) ----
    {
        const unsigned short* mg = Mt + (long)b * On * Dn;
        uint4 vbuf[8];
        #pragma unroll
        for (int i = 0; i < 8; ++i)
            vbuf[i] = *(const uint4*)(mg + (i * 512 + t) * 8);
        #pragma unroll
        for (int i = 0; i < 8; ++i) {
            const int ch = i * 512 + t;
            const int o = ch >> 4, kc = ch & 15;
            *(uint4*)&MtL[o * 128 + ((kc ^ (o & 15)) * 8)] = vbuf[i];
        }
    }

    // ---- B fragments from x1 (independent of LDS stage) ----
    s16x8 bfr[4];
    float rs = 0.f;
    const float* xrow = x1 + ((long)b * Nn + row) * Dn;
    #pragma unroll
    for (int kk = 0; kk < 4; ++kk) {
        const float* p = xrow + kk * 32 + g * 8;
        f32x4 v0 = *(const f32x4*)p;
        f32x4 v1 = *(const f32x4*)(p + 4);
        s16x8 bb;
        #pragma unroll
        for (int j = 0; j < 4; ++j) {
            float e0 = __expf(v0[j]), e1 = __expf(v1[j]);
            rs += e0 + e1;
            bb[j]     = (short)f2bf(e0);
            bb[j + 4] = (short)f2bf(e1);
        }
        bfr[kk] = bb;
    }
    rs += __shfl_xor(rs, 16);
    rs += __shfl_xor(rs, 32);
    const float inv = 1.0f / rs;

    __syncthreads();

    // ---- MFMA: A from LDS ----
    f32x4 acc[16];
    #pragma unroll
    for (int nt = 0; nt < 16; ++nt) {
        const int o = nt * 16 + c;
        const unsigned short* ap = &MtL[o * 128];
        f32x4 a4 = (f32x4){0.f, 0.f, 0.f, 0.f};
        #pragma unroll
        for (int kk = 0; kk < 4; ++kk) {
            s16x8 af = *(const s16x8*)(ap + (((kk * 4 + g) ^ c) * 8));
            a4 = __builtin_amdgcn_mfma_f32_16x16x32_bf16(af, bfr[kk], a4, 0, 0, 0);
        }
        acc[nt] = a4;
    }

    // ---- epilogue: eff = acc*inv + bias; LN over o (256) per row ----
    float sm = 0.f, ssq = 0.f;
    #pragma unroll
    for (int nt = 0; nt < 16; ++nt) {
        f32x4 bv = *(const f32x4*)(bias + nt * 16 + g * 4);
        #pragma unroll
        for (int r = 0; r < 4; ++r) {
            float e = acc[nt][r] * inv + bv[r];
            acc[nt][r] = e;
            sm += e;
            ssq += e * e;
        }
    }
    sm  += __shfl_xor(sm, 16);  sm  += __shfl_xor(sm, 32);
    ssq += __shfl_xor(ssq, 16); ssq += __shfl_xor(ssq, 32);
    const float mean = sm * (1.0f / 256.0f);
    const float rstd = rsqrtf(ssq * (1.0f / 256.0f) - mean * mean + LN_EPS);

    // fold gamma/beta in-register
    #pragma unroll
    for (int nt = 0; nt < 16; ++nt) {
        f32x4 gm = *(const f32x4*)(gamma + nt * 16 + g * 4);
        f32x4 bt = *(const f32x4*)(beta  + nt * 16 + g * 4);
        #pragma unroll
        for (int r = 0; r < 4; ++r)
            acc[nt][r] = (acc[nt][r] - mean) * rstd * gm[r] + bt[r];
    }

    __syncthreads();   // all waves done reading MtL fragments -> reuse as float buf

    // ---- output transpose through LDS; full-line global stores ----
    float* wb = (float*)MtL + wave * 2048;
    const int rowbase = blockIdx.x * 128 + wave * 16;
    float* ob = out + ((long)b * Nn + rowbase) * On;

    #pragma unroll
    for (int h = 0; h < 2; ++h) {
        #pragma unroll
        for (int ntp = 0; ntp < 8; ++ntp) {
            const int cc = ntp * 4 + g;
            const int sw = (cc & ~7) | ((cc & 7) ^ (c & 7));
            *(f32x4*)&wb[c * 128 + sw * 4] = acc[h * 8 + ntp];
        }
        #pragma unroll
        for (int i = 0; i < 8; ++i) {
            const int r = (lane >> 3) + (i & 1) * 8;
            const int L = i >> 1;
            const int j = lane & 7;
            const f32x4 v = *(const f32x4*)&wb[r * 128 + (L * 8 + (j ^ (r & 7))) * 4];
            *(f32x4*)&ob[(long)r * On + h * 128 + L * 32 + j * 4] = v;
        }
    }
}

extern "C" void kernel_launch(void* const* d_in, const int* in_sizes, int n_in,
                              void* d_out, int out_size, void* d_ws, size_t ws_size,
                              hipStream_t stream)
{
    const float* x1    = (const float*)d_in[0];
    const float* x2    = (const float*)d_in[1];
    const float* w     = (const float*)d_in[2];
    const float* bias  = (const float*)d_in[3];
    const float* gamma = (const float*)d_in[4];
    const float* beta  = (const float*)d_in[5];
    float* out = (float*)d_out;

    // workspace layout: no memset needed (every byte read is written first)
    float* ctx_part = (float*)d_ws;                                // 8*64*128*128 f32 = 32 MB
    float* cs_part  = (float*)((char*)d_ws + 33554432);            // 8*64*128 f32 = 256 KB
    float* ctx      = (float*)((char*)d_ws + 33816576);            // 8*128*128 f32 = 512 KB
    float* cs       = (float*)((char*)d_ws + 34340864);            // 8*128 f32 = 4 KB
    unsigned short* Mt = (unsigned short*)((char*)d_ws + 34344960);// 8*256*128 bf16 = 512 KB

    k_context<<<dim3(64, 8), 256, 0, stream>>>(x1, x2, ctx_part, cs_part);
    k_reduce<<<dim3(128), 256, 0, stream>>>(ctx_part, cs_part, ctx, cs);
    k_mt<<<dim3(On / 2, 8), 256, 0, stream>>>(ctx, cs, w, Mt);
    k_main<<<dim3(128, 8), 512, 0, stream>>>(x1, Mt, bias, gamma, beta, out);
}

// Round 6
// 292.150 us; speedup vs baseline: 1.0300x; 1.0300x over previous
//
#include <hip/hip_runtime.h>
#include <stdint.h>

constexpr int Bn = 8;
constexpr int Nn = 16384;
constexpr int Dn = 128;
constexpr int On = 256;
#define LN_EPS 1e-5f

typedef float  f32x4 __attribute__((ext_vector_type(4)));
typedef short  s16x8 __attribute__((ext_vector_type(8)));

__device__ __forceinline__ unsigned short f2bf(float f) {
    union { float f; unsigned u; } v; v.f = f;
    unsigned r = v.u + 0x7FFFu + ((v.u >> 16) & 1u);   // RNE
    return (unsigned short)(r >> 16);
}
__device__ __forceinline__ float bf2f(unsigned short s) {
    unsigned u = ((unsigned)s) << 16;
    float f; __builtin_memcpy(&f, &u, 4);
    return f;
}

// ------------------------------------------------------------------
// K2 v7: 32 chunks x 512 n (grid 256 = 1 block/CU), register-pipelined
// n-loop (r5), and FULL-LINE partial stores via per-wave LDS transpose.
// Rationale (r5 post-mortem): our kernels total only ~60 us (3 fills
// = 240 us fixed); k_context's remaining slack is ctx_part traffic:
// 64 partials = 32 MB RT plus ~32 MB write-allocate RMW fetch from the
// 64B-granular scatter stores (r3 proved this RMW pattern on k_main).
// 32 chunks + LDS-transposed stores: 64 MB+RMW -> 32 MB, full lines.
// ------------------------------------------------------------------
__global__ __launch_bounds__(256) void k_context(
    const float* __restrict__ x1, const float* __restrict__ x2,
    float* __restrict__ ctx_part, float* __restrict__ cs_part)
{
    __shared__ unsigned short As[128][72];
    __shared__ unsigned short Bs[128][72];
    __shared__ float cs_scr[256];
    __shared__ float obuf[4][32][132];   // per-wave transpose buffer (pad 132: 2-way max on writes)

    const int b     = blockIdx.y;
    const int chunk = blockIdx.x;          // 0..31
    const int t     = threadIdx.x;
    const int wave  = t >> 6;
    const int lane  = t & 63;
    const int c     = lane & 15, g = lane >> 4;

    const int n_base = chunk * 512;

    f32x4 acc[2][8];
    #pragma unroll
    for (int i = 0; i < 2; ++i)
        #pragma unroll
        for (int j = 0; j < 8; ++j) acc[i][j] = (f32x4){0.f,0.f,0.f,0.f};

    const int dg = t >> 5, rg = t & 31;
    const int d0 = dg * 16;

    float cs_acc = 0.f;
    const int cd = t & 127, half = t >> 7;

    const float* p1base = x1 + (((long)b * Nn + n_base + 2 * rg) * Dn + d0);
    const float* p2base = x2 + (((long)b * Nn + n_base + 2 * rg) * Dn + d0);

    f32x4 r1a[4], r1b[4], r2a[4], r2b[4];
    // prologue: load sc=0
    #pragma unroll
    for (int j = 0; j < 4; ++j) {
        r1a[j] = *(const f32x4*)(p1base + j * 4);
        r1b[j] = *(const f32x4*)(p1base + Dn + j * 4);
        r2a[j] = *(const f32x4*)(p2base + j * 4);
        r2b[j] = *(const f32x4*)(p2base + Dn + j * 4);
    }

    for (int sc = 0; sc < 8; ++sc) {
        // ---- pack current regs -> LDS ----
        #pragma unroll
        for (int j = 0; j < 4; ++j) {
            #pragma unroll
            for (int jj = 0; jj < 4; ++jj) {
                const int d = d0 + j * 4 + jj;
                unsigned ua = (unsigned)f2bf(__expf(r1a[j][jj])) |
                              ((unsigned)f2bf(__expf(r1b[j][jj])) << 16);
                unsigned ub = (unsigned)f2bf(r2a[j][jj]) |
                              ((unsigned)f2bf(r2b[j][jj]) << 16);
                *(unsigned*)&As[d][2 * rg] = ua;
                *(unsigned*)&Bs[d][2 * rg] = ub;
            }
        }
        __syncthreads();

        // ---- issue next sub-chunk's loads; they fly under MFMA+cs ----
        if (sc < 7) {
            const float* p1 = p1base + (long)(sc + 1) * 64 * Dn;
            const float* p2 = p2base + (long)(sc + 1) * 64 * Dn;
            #pragma unroll
            for (int j = 0; j < 4; ++j) {
                r1a[j] = *(const f32x4*)(p1 + j * 4);
                r1b[j] = *(const f32x4*)(p1 + Dn + j * 4);
                r2a[j] = *(const f32x4*)(p2 + j * 4);
                r2b[j] = *(const f32x4*)(p2 + Dn + j * 4);
            }
        }

        // ---- cs-sum + MFMA from LDS ----
        #pragma unroll
        for (int j = 0; j < 4; ++j) {
            const s16x8 e = *(const s16x8*)&As[cd][half * 32 + j * 8];
            #pragma unroll
            for (int jj = 0; jj < 8; ++jj)
                cs_acc += bf2f((unsigned short)e[jj]);
        }
        #pragma unroll
        for (int kk = 0; kk < 2; ++kk) {
            s16x8 a[2], bb[8];
            #pragma unroll
            for (int mt = 0; mt < 2; ++mt)
                a[mt] = *(const s16x8*)&As[wave * 32 + mt * 16 + c][kk * 32 + g * 8];
            #pragma unroll
            for (int nt = 0; nt < 8; ++nt)
                bb[nt] = *(const s16x8*)&Bs[nt * 16 + c][kk * 32 + g * 8];
            #pragma unroll
            for (int mt = 0; mt < 2; ++mt)
                #pragma unroll
                for (int nt = 0; nt < 8; ++nt)
                    acc[mt][nt] = __builtin_amdgcn_mfma_f32_16x16x32_bf16(
                        a[mt], bb[nt], acc[mt][nt], 0, 0, 0);
        }
        __syncthreads();
    }

    cs_scr[t] = cs_acc;
    __syncthreads();
    if (t < 128)
        cs_part[((long)(b * 32 + chunk)) * 128 + t] = cs_scr[t] + cs_scr[t + 128];

    // ---- partial tile store: per-wave LDS transpose -> full-line stores ----
    // wave w owns d rows [w*32, w*32+32); write its 32x128 slab to obuf[w],
    // then read back f32x4 and store 128B-line-aligned. Same-wave ds order
    // is handled by compiler-inserted lgkmcnt; no block barrier needed.
    #pragma unroll
    for (int mt = 0; mt < 2; ++mt)
        #pragma unroll
        for (int nt = 0; nt < 8; ++nt)
            #pragma unroll
            for (int r = 0; r < 4; ++r)
                obuf[wave][mt * 16 + g * 4 + r][nt * 16 + c] = acc[mt][nt][r];

    float* cp = ctx_part + ((long)(b * 32 + chunk)) * 16384 + wave * 32 * 128;
    #pragma unroll
    for (int ro = 0; ro < 4; ++ro)
        #pragma unroll
        for (int ci = 0; ci < 4; ++ci) {
            const int row = ro * 8 + (lane >> 3);
            const int jb  = ci * 8 + (lane & 7);
            const f32x4 v = *(const f32x4*)&obuf[wave][row][jb * 4];
            *(f32x4*)&cp[row * 128 + jb * 4] = v;   // 8 lanes = one full 128B line
        }
}

// ------------------------------------------------------------------
// K2b v3: reduce 32 chunk-partials -> ctx [b][d][v], cs [b][d].
// 16.5 MB reads (L3-resident) + 0.5 MB writes.
// ------------------------------------------------------------------
__global__ __launch_bounds__(256) void k_reduce(
    const float* __restrict__ ctx_part, const float* __restrict__ cs_part,
    float* __restrict__ ctx, float* __restrict__ cs)
{
    const int gid = blockIdx.x * 256 + threadIdx.x;   // 0..32767
    const long F  = (long)gid * 4;
    const int b   = gid >> 12;
    const int f   = (int)(F & 16383);

    const float* base = ctx_part + (long)b * 524288 + f;
    f32x4 s = (f32x4){0.f, 0.f, 0.f, 0.f};
    #pragma unroll 8
    for (int ck = 0; ck < 32; ++ck) {
        f32x4 v = *(const f32x4*)(base + (long)ck * 16384);
        s[0] += v[0]; s[1] += v[1]; s[2] += v[2]; s[3] += v[3];
    }
    *(f32x4*)(ctx + F) = s;

    if (gid < 1024) {
        const int bb = gid >> 7, d = gid & 127;
        const float* cb = cs_part + (long)bb * 4096 + d;
        float sc = 0.f;
        #pragma unroll 8
        for (int ck = 0; ck < 32; ++ck) sc += cb[ck * 128];
        cs[gid] = sc;
    }
}

// ------------------------------------------------------------------
// K3 v2 (unchanged): Mt[b][o][d] = bf16( (ctx[b][d][:] . w[o][:]) / cs[b][d] )
// ------------------------------------------------------------------
__global__ __launch_bounds__(256) void k_mt(
    const float* __restrict__ ctx, const float* __restrict__ cs,
    const float* __restrict__ w, unsigned short* __restrict__ Mt)
{
    const int b = blockIdx.y;
    const int t = threadIdx.x;
    const int o = blockIdx.x * 2 + (t >> 7);
    const int d = t & 127;

    const float* crow = ctx + ((long)b * 128 + d) * 128;
    const float* wrow = w + (long)o * 128;

    float s0 = 0.f, s1 = 0.f, s2 = 0.f, s3 = 0.f;
    #pragma unroll
    for (int v = 0; v < 128; v += 16) {
        f32x4 c0 = *(const f32x4*)(crow + v);
        f32x4 c1 = *(const f32x4*)(crow + v + 4);
        f32x4 c2 = *(const f32x4*)(crow + v + 8);
        f32x4 c3 = *(const f32x4*)(crow + v + 12);
        f32x4 w0 = *(const f32x4*)(wrow + v);
        f32x4 w1 = *(const f32x4*)(wrow + v + 4);
        f32x4 w2 = *(const f32x4*)(wrow + v + 8);
        f32x4 w3 = *(const f32x4*)(wrow + v + 12);
        s0 += c0[0]*w0[0] + c0[1]*w0[1] + c0[2]*w0[2] + c0[3]*w0[3];
        s1 += c1[0]*w1[0] + c1[1]*w1[1] + c1[2]*w1[2] + c1[3]*w1[3];
        s2 += c2[0]*w2[0] + c2[1]*w2[1] + c2[2]*w2[2] + c2[3]*w2[3];
        s3 += c3[0]*w3[0] + c3[1]*w3[1] + c3[2]*w3[2] + c3[3]*w3[3];
    }
    const float s = (s0 + s1) + (s2 + s3);
    Mt[((long)b * On + o) * 128 + d] = f2bf(s / cs[b * 128 + d]);
}

// ------------------------------------------------------------------
// K4 v5 (unchanged from round 4): full-line output stores via LDS
// transpose (MtL reuse). Verified r4: removed write-allocate RMW.
// ------------------------------------------------------------------
__global__ __launch_bounds__(512, 4) void k_main(
    const float* __restrict__ x1, const unsigned short* __restrict__ Mt,
    const float* __restrict__ bias, const float* __restrict__ gamma,
    const float* __restrict__ beta, float* __restrict__ out)
{
    __shared__ unsigned short MtL[256 * 128];   // 64 KiB; reused as out-stage

    const int b    = blockIdx.y;
    const int t    = threadIdx.x;
    const int wave = t >> 6, lane = t & 63;
    const int c    = lane & 15, g = lane >> 4;
    const int row  = blockIdx.x * 128 + wave * 16 + c;

    // ---- stage Mt -> LDS (swizzled) ----
    {
        const unsigned short* mg = Mt + (long)b * On * Dn;
        uint4 vbuf[8];
        #pragma unroll
        for (int i = 0; i < 8; ++i)
            vbuf[i] = *(const uint4*)(mg + (i * 512 + t) * 8);
        #pragma unroll
        for (int i = 0; i < 8; ++i) {
            const int ch = i * 512 + t;
            const int o = ch >> 4, kc = ch & 15;
            *(uint4*)&MtL[o * 128 + ((kc ^ (o & 15)) * 8)] = vbuf[i];
        }
    }

    // ---- B fragments from x1 (independent of LDS stage) ----
    s16x8 bfr[4];
    float rs = 0.f;
    const float* xrow = x1 + ((long)b * Nn + row) * Dn;
    #pragma unroll
    for (int kk = 0; kk < 4; ++kk) {
        const float* p = xrow + kk * 32 + g * 8;
        f32x4 v0 = *(const f32x4*)p;
        f32x4 v1 = *(const f32x4*)(p + 4);
        s16x8 bb;
        #pragma unroll
        for (int j = 0; j < 4; ++j) {
            float e0 = __expf(v0[j]), e1 = __expf(v1[j]);
            rs += e0 + e1;
            bb[j]     = (short)f2bf(e0);
            bb[j + 4] = (short)f2bf(e1);
        }
        bfr[kk] = bb;
    }
    rs += __shfl_xor(rs, 16);
    rs += __shfl_xor(rs, 32);
    const float inv = 1.0f / rs;

    __syncthreads();

    // ---- MFMA: A from LDS ----
    f32x4 acc[16];
    #pragma unroll
    for (int nt = 0; nt < 16; ++nt) {
        const int o = nt * 16 + c;
        const unsigned short* ap = &MtL[o * 128];
        f32x4 a4 = (f32x4){0.f, 0.f, 0.f, 0.f};
        #pragma unroll
        for (int kk = 0; kk < 4; ++kk) {
            s16x8 af = *(const s16x8*)(ap + (((kk * 4 + g) ^ c) * 8));
            a4 = __builtin_amdgcn_mfma_f32_16x16x32_bf16(af, bfr[kk], a4, 0, 0, 0);
        }
        acc[nt] = a4;
    }

    // ---- epilogue: eff = acc*inv + bias; LN over o (256) per row ----
    float sm = 0.f, ssq = 0.f;
    #pragma unroll
    for (int nt = 0; nt < 16; ++nt) {
        f32x4 bv = *(const f32x4*)(bias + nt * 16 + g * 4);
        #pragma unroll
        for (int r = 0; r < 4; ++r) {
            float e = acc[nt][r] * inv + bv[r];
            acc[nt][r] = e;
            sm += e;
            ssq += e * e;
        }
    }
    sm  += __shfl_xor(sm, 16);  sm  += __shfl_xor(sm, 32);
    ssq += __shfl_xor(ssq, 16); ssq += __shfl_xor(ssq, 32);
    const float mean = sm * (1.0f / 256.0f);
    const float rstd = rsqrtf(ssq * (1.0f / 256.0f) - mean * mean + LN_EPS);

    // fold gamma/beta in-register
    #pragma unroll
    for (int nt = 0; nt < 16; ++nt) {
        f32x4 gm = *(const f32x4*)(gamma + nt * 16 + g * 4);
        f32x4 bt = *(const f32x4*)(beta  + nt * 16 + g * 4);
        #pragma unroll
        for (int r = 0; r < 4; ++r)
            acc[nt][r] = (acc[nt][r] - mean) * rstd * gm[r] + bt[r];
    }

    __syncthreads();   // all waves done reading MtL fragments -> reuse as float buf

    // ---- output transpose through LDS; full-line global stores ----
    float* wb = (float*)MtL + wave * 2048;
    const int rowbase = blockIdx.x * 128 + wave * 16;
    float* ob = out + ((long)b * Nn + rowbase) * On;

    #pragma unroll
    for (int h = 0; h < 2; ++h) {
        #pragma unroll
        for (int ntp = 0; ntp < 8; ++ntp) {
            const int cc = ntp * 4 + g;
            const int sw = (cc & ~7) | ((cc & 7) ^ (c & 7));
            *(f32x4*)&wb[c * 128 + sw * 4] = acc[h * 8 + ntp];
        }
        #pragma unroll
        for (int i = 0; i < 8; ++i) {
            const int r = (lane >> 3) + (i & 1) * 8;
            const int L = i >> 1;
            const int j = lane & 7;
            const f32x4 v = *(const f32x4*)&wb[r * 128 + (L * 8 + (j ^ (r & 7))) * 4];
            *(f32x4*)&ob[(long)r * On + h * 128 + L * 32 + j * 4] = v;
        }
    }
}

extern "C" void kernel_launch(void* const* d_in, const int* in_sizes, int n_in,
                              void* d_out, int out_size, void* d_ws, size_t ws_size,
                              hipStream_t stream)
{
    const float* x1    = (const float*)d_in[0];
    const float* x2    = (const float*)d_in[1];
    const float* w     = (const float*)d_in[2];
    const float* bias  = (const float*)d_in[3];
    const float* gamma = (const float*)d_in[4];
    const float* beta  = (const float*)d_in[5];
    float* out = (float*)d_out;

    // workspace layout: no memset needed (every byte read is written first)
    float* ctx_part = (float*)d_ws;                                // 8*32*128*128 f32 = 16 MB
    float* cs_part  = (float*)((char*)d_ws + 16777216);            // 8*32*128 f32 = 128 KB
    float* ctx      = (float*)((char*)d_ws + 16908288);            // 8*128*128 f32 = 512 KB
    float* cs       = (float*)((char*)d_ws + 17432576);            // 8*128 f32 = 4 KB
    unsigned short* Mt = (unsigned short*)((char*)d_ws + 17436672);// 8*256*128 bf16 = 512 KB

    k_context<<<dim3(32, 8), 256, 0, stream>>>(x1, x2, ctx_part, cs_part);
    k_reduce<<<dim3(128), 256, 0, stream>>>(ctx_part, cs_part, ctx, cs);
    k_mt<<<dim3(On / 2, 8), 256, 0, stream>>>(ctx, cs, w, Mt);
    k_main<<<dim3(128, 8), 512, 0, stream>>>(x1, Mt, bias, gamma, beta, out);
}